// Round 7
// baseline (578.515 us; speedup 1.0000x reference)
//
#include <hip/hip_runtime.h>
#include <cmath>
#include <complex>

#define BT 16   // batch tile per block
#define NP 11   // number of tensor-product paths

// ---- path metadata (compile-time) ----------------------------------------
// paths in reference order: (i1,i2,io) =
// (0,0,0),(0,1,1),(0,2,2),(1,0,1),(1,1,0),(1,1,2),(1,2,1),(2,0,2),(2,1,1),(2,2,0),(2,2,2)
constexpr int P_N1[NP]   = {1,1,1, 3,3,3,3, 5,5,5,5};              // 2*l1+1
constexpr int P_N2[NP]   = {1,3,5, 1,3,3,5, 1,3,5,5};              // 2*l2+1
constexpr int P_NO[NP]   = {1,3,5, 3,1,5,3, 5,3,1,5};              // 2*lo+1
constexpr int P_S1[NP]   = {0,0,0, 128,128,128,128, 512,512,512,512}; // x1 offset
constexpr int P_S2[NP]   = {0,1,4, 0,1,1,4, 0,1,4,4};              // x2 offset
constexpr int P_MOFF[NP] = {0,1,4,9,18,21,36,45,70,85,90};         // M LDS offsets (sizes no*n1, total 115)
constexpr int P_W3J[NP]  = {0,1,10,35,44,53,98,143,168,213,238};   // w3j offsets (sizes n1*n2*no, total 363)

#define WPLANE 180224          // 11*128*128 bf16 elements per plane (hi / lo)

struct TPConst {
    float w3j[363];
    float sqa[11];
};

// ---- host-side exact mirror of the reference w3j computation -------------
namespace {

double hfact(int n) { double r = 1.0; for (int i = 2; i <= n; ++i) r *= (double)i; return r; }

void hsu2cg(int j1, int j2, int j3, double* C) {
    const int d2 = 2*j2+1, d3 = 2*j3+1, d1 = 2*j1+1;
    for (int i = 0; i < d1*d2*d3; ++i) C[i] = 0.0;
    for (int m1 = -j1; m1 <= j1; ++m1)
        for (int m2 = -j2; m2 <= j2; ++m2) {
            const int m3 = m1 + m2;
            if (m3 < -j3 || m3 > j3) continue;
            double pref = std::sqrt((2*j3+1) * hfact(j3+j1-j2) * hfact(j3-j1+j2) * hfact(j1+j2-j3) / hfact(j1+j2+j3+1));
            pref *= std::sqrt(hfact(j3+m3)*hfact(j3-m3)*hfact(j1-m1)*hfact(j1+m1)*hfact(j2-m2)*hfact(j2+m2));
            double s = 0.0;
            for (int k = 0; k <= j1+j2-j3; ++k) {
                if (j1-m1-k < 0 || j2+m2-k < 0 || j3-j2+m1+k < 0 || j3-j1-m2+k < 0) continue;
                double d = hfact(k)*hfact(j1+j2-j3-k)*hfact(j1-m1-k)*hfact(j2+m2-k)*hfact(j3-j2+m1+k)*hfact(j3-j1-m2+k);
                s += ((k & 1) ? -1.0 : 1.0) / d;
            }
            C[((j1+m1)*d2 + (j2+m2))*d3 + (j3+m3)] = pref * s;
        }
}

void hrealbasis(int l, std::complex<double>* q) {  // (2l+1)x(2l+1), row-major
    const int d = 2*l+1;
    for (int i = 0; i < d*d; ++i) q[i] = 0.0;
    const double is2 = 1.0 / std::sqrt(2.0);
    for (int m = -l; m < 0; ++m) {
        q[(l+m)*d + (l - m)] = is2;                                  // l+|m| = l-m for m<0
        q[(l+m)*d + (l + m)] = std::complex<double>(0.0, -is2);      // l-|m| = l+m
    }
    q[l*d + l] = 1.0;
    for (int m = 1; m <= l; ++m) {
        const double sgn = (m & 1) ? -1.0 : 1.0;
        q[(l+m)*d + (l + m)] = sgn * is2;
        q[(l+m)*d + (l - m)] = std::complex<double>(0.0, sgn * is2);
    }
    std::complex<double> ph(1.0, 0.0);
    const std::complex<double> mi(0.0, -1.0);
    for (int i = 0; i < l; ++i) ph *= mi;   // (-i)^l
    for (int i = 0; i < d*d; ++i) q[i] *= ph;
}

void hw3j(int l1, int l2, int l3, float* out) {
    const int d1 = 2*l1+1, d2 = 2*l2+1, d3 = 2*l3+1;
    double C[125];
    hsu2cg(l1, l2, l3, C);
    std::complex<double> Q1[25], Q2[25], Q3[25];
    hrealbasis(l1, Q1); hrealbasis(l2, Q2); hrealbasis(l3, Q3);
    double R[125]; double norm2 = 0.0;
    for (int j = 0; j < d1; ++j)
        for (int l = 0; l < d2; ++l)
            for (int m = 0; m < d3; ++m) {
                std::complex<double> s(0.0, 0.0);
                for (int i = 0; i < d1; ++i)
                    for (int k = 0; k < d2; ++k)
                        for (int n = 0; n < d3; ++n)
                            s += Q1[i*d1 + j] * Q2[k*d2 + l] * std::conj(Q3[n*d3 + m]) * C[(i*d2 + k)*d3 + n];
                R[(j*d2 + l)*d3 + m] = s.real();
                norm2 += s.real() * s.real();
            }
    const double inv = 1.0 / std::sqrt(norm2);
    for (int i = 0; i < d1*d2*d3; ++i) out[i] = (float)(R[i] * inv);
}

void fill_const(TPConst& tc) {
    const int L1[NP] = {0,0,0,1,1,1,1,2,2,2,2};
    const int L2[NP] = {0,1,2,0,1,1,2,0,1,2,2};
    const int LO[NP] = {0,1,2,1,0,2,1,2,1,0,2};
    const double den[3] = {384.0, 512.0, 512.0};   // path_normalization='element'
    for (int p = 0; p < NP; ++p) {
        hw3j(L1[p], L2[p], LO[p], tc.w3j + P_W3J[p]);
        tc.sqa[p] = (float)std::sqrt((2.0*LO[p] + 1.0) / den[LO[p]]);
    }
}

}  // namespace

// ---- device types / helpers ----------------------------------------------
typedef __attribute__((ext_vector_type(8))) short  short8v;   // 8 bf16 (4 VGPRs), MFMA A/B frag
typedef __attribute__((ext_vector_type(4))) float  f32x4;     // MFMA C/D frag

__device__ __forceinline__ unsigned fbits(float f) { return __builtin_bit_cast(unsigned, f); }
__device__ __forceinline__ float    bitsf(unsigned u) { return __builtin_bit_cast(float, u); }

// hi/lo bf16 split: hi = truncated top-16, lo = bf16(exact residual).
// Captured precision ~17 mantissa bits.
__device__ __forceinline__ void splitf(float f, unsigned short& h, unsigned short& l) {
    const unsigned ub = fbits(f);
    h = (unsigned short)(ub >> 16);
    const float r = f - bitsf(ub & 0xFFFF0000u);
    l = (unsigned short)(fbits(r) >> 16);
}

// ---- W prep kernel: wsg [p][u][w] fp32 -> whl [p][w][u] bf16 hi + lo -----
// Runs once per launch (720896 B in d_ws). Removes the per-wave in-register
// W split that was ~half the round-6 VALU load (2048x redundant).
__global__ __launch_bounds__(256)
void w_prep(const float* __restrict__ wsg, unsigned short* __restrict__ whl)
{
    const int idx = blockIdx.x*256 + threadIdx.x;   // [p][w][u]
    if (idx >= WPLANE) return;
    const int u = idx & 127, w = (idx >> 7) & 127, p = idx >> 14;
    const float f = wsg[(p*128 + u)*128 + w];
    unsigned short h, l;
    splitf(f, h, l);
    whl[idx] = h;
    whl[WPLANE + idx] = l;
}

// ---- phase B: y into LDS slot(s) ------------------------------------------
// ROUND-4 LESSON (rule #20): all path/slot/k indices are template params —
// compile-time-ness never depends on unroll heuristics.
// y layout: [slot][b][u] bf16 (hi+lo planes), u XOR-swizzled by (b&7)<<3
// (un-swizzled, the 16 b-rows at 256 B stride are a 16-way conflict on the
// frag reads; swizzled it's 2-way = free [m136]).
template<int P, int K0, int NOK, int S0>
__device__ __forceinline__ void tp_yb(
    const float* __restrict__ x1, const float (*__restrict__ Mlds)[116],
    unsigned short* __restrict__ yhi, unsigned short* __restrict__ ylo,
    long b0, int uy, int g)
{
    constexpr int n1 = P_N1[P];
    #pragma unroll
    for (int bb = 0; bb < 8; ++bb) {
        const int b = g*8 + bb;
        const float* xp = x1 + (b0 + b)*1152 + P_S1[P] + uy*n1;
        float xv[5];
        #pragma unroll
        for (int i = 0; i < n1; ++i) xv[i] = xp[i];
        const int us = uy ^ ((b & 7) << 3);
        #pragma unroll
        for (int kl = 0; kl < NOK; ++kl) {
            float yv = 0.f;
            #pragma unroll
            for (int i = 0; i < n1; ++i)
                yv += Mlds[b][P_MOFF[P] + (K0 + kl)*n1 + i] * xv[i];
            unsigned short h, l;
            splitf(yv, h, l);
            yhi[((S0 + kl)*16 + b)*128 + us] = h;
            ylo[((S0 + kl)*16 + b)*128 + us] = l;
        }
    }
}

// ---- phase C: MFMA unit ---------------------------------------------------
// GEMM tile per block: C[w,(b,k)] += sum_u W_p[u,w] * y[b,u,k]
// mfma_f32_16x16x32_bf16; A-frag = prepped Whi/Wlo (16B contiguous load,
// L1-resident), B-frag from LDS slots. fp32 via 3 products (hh + hl + lh).
// Lane layouts verified on HW in round 6 (passed at fp32-level absmax).
template<int P, int K0, int NOK, int S0, int NA>
__device__ __forceinline__ void tp_mc(
    const unsigned short* __restrict__ whl,
    const unsigned short* __restrict__ yhi, const unsigned short* __restrict__ ylo,
    f32x4 (&acc)[2][NA], int lane, int wv)
{
    const int bC = lane & 15, qC = lane >> 4;
    #pragma unroll
    for (int k4 = 0; k4 < 4; ++k4) {
        const int ubase = k4*32 + qC*8;
        short8v Ah[2], Al[2];
        #pragma unroll
        for (int mt = 0; mt < 2; ++mt) {
            const int aoff = (P*128 + (wv*32 + mt*16 + bC))*128 + ubase;
            Ah[mt] = *(const short8v*)(whl + aoff);
            Al[mt] = *(const short8v*)(whl + WPLANE + aoff);
        }
        const int uoff = ubase ^ ((bC & 7) << 3);
        #pragma unroll
        for (int kl = 0; kl < NOK; ++kl) {
            const int ridx = ((S0 + kl)*16 + bC)*128 + uoff;
            const short8v Bh = *(const short8v*)(yhi + ridx);
            const short8v Bl = *(const short8v*)(ylo + ridx);
            #pragma unroll
            for (int mt = 0; mt < 2; ++mt) {
                acc[mt][K0+kl] = __builtin_amdgcn_mfma_f32_16x16x32_bf16(Ah[mt], Bh, acc[mt][K0+kl], 0, 0, 0);
                acc[mt][K0+kl] = __builtin_amdgcn_mfma_f32_16x16x32_bf16(Ah[mt], Bl, acc[mt][K0+kl], 0, 0, 0);
                acc[mt][K0+kl] = __builtin_amdgcn_mfma_f32_16x16x32_bf16(Al[mt], Bh, acc[mt][K0+kl], 0, 0, 0);
            }
        }
    }
}

// ---- main kernel ----------------------------------------------------------
// Software pipeline: 17 units, each inter-barrier region = {MFMA of unit i
// || phase-B of unit i+1} on DISJOINT compile-time y-slots (5 slots total,
// verified rotation: {0,1,2} -> {3,4}/{0} alternation -> {2,3,4}/{0,1}).
// Phase B's global loads + fmacs + ds_writes hide under the matrix pipe.
// LDS: Mlds 7424 + 2*20480 = 48384 B -> 3 blocks/CU.
// (256,2) caps VGPR at 128 (calibrated r1-r3: (256,3)->84 spills huge;
// plain->132 crosses the 128 HW allocation boundary and halves residency).
__global__ __launch_bounds__(256, 2)
void tp_kernel(const float* __restrict__ x1, const float* __restrict__ x2,
               const unsigned short* __restrict__ whl, float* __restrict__ out,
               TPConst tc)
{
    __shared__ float Mlds[BT][116];                         // per-b M matrices (scaled), 115 used
    __shared__ __align__(16) unsigned short yhi[5*16*128];  // y hi-plane, [slot][b][u] swizzled
    __shared__ __align__(16) unsigned short ylo[5*16*128];  // y lo-plane

    const int t = threadIdx.x;
    const long b0 = (long)blockIdx.x * BT;

    // Phase A: M_p[b][k][i] = sum_j C_p[i][j][k] * x2[b][s2+j], scaled
    if (t < BT) {
        float x2v[9];
        #pragma unroll
        for (int j = 0; j < 9; ++j) x2v[j] = x2[(b0 + t)*9 + j];
        #pragma unroll
        for (int p = 0; p < NP; ++p) {
            const int n1 = P_N1[p], n2 = P_N2[p], no = P_NO[p];
            const float sqa = tc.sqa[p];
            #pragma unroll
            for (int k = 0; k < no; ++k)
                #pragma unroll
                for (int i = 0; i < n1; ++i) {
                    float m = 0.f;
                    #pragma unroll
                    for (int j = 0; j < n2; ++j)
                        m += tc.w3j[P_W3J[p] + (i*n2 + j)*no + k] * x2v[P_S2[p] + j];
                    Mlds[t][P_MOFF[p] + k*n1 + i] = m * sqa;
                }
        }
    }

    const int uy = t & 127, g = t >> 7;      // phase B roles
    const int lane = t & 63, wv = t >> 6;    // phase C roles
    const int bC = lane & 15, qC = lane >> 4;
    float* opb = out + (b0 + bC)*1152;

    __syncthreads();

    // U0 phase B: pass-0 paths 0,4,9 into slots 0,1,2
    tp_yb<0,0,1,0>(x1, Mlds, yhi, ylo, b0, uy, g);
    tp_yb<4,0,1,1>(x1, Mlds, yhi, ylo, b0, uy, g);
    tp_yb<9,0,1,2>(x1, Mlds, yhi, ylo, b0, uy, g);
    __syncthreads();

    f32x4 acc0[2][1];
    f32x4 acc1[2][3];
    #pragma unroll
    for (int mt = 0; mt < 2; ++mt) {
        acc0[mt][0] = f32x4{0.f,0.f,0.f,0.f};
        #pragma unroll
        for (int k = 0; k < 3; ++k) acc1[mt][k] = f32x4{0.f,0.f,0.f,0.f};
    }

    // R0: C(U0 @ s0-2) || B(U1: p1 k01 -> s3,4)
    tp_mc<0,0,1,0,1>(whl, yhi, ylo, acc0, lane, wv);
    tp_mc<4,0,1,1,1>(whl, yhi, ylo, acc0, lane, wv);
    tp_mc<9,0,1,2,1>(whl, yhi, ylo, acc0, lane, wv);
    tp_yb<1,0,2,3>(x1, Mlds, yhi, ylo, b0, uy, g);
    __syncthreads();

    // R1: C(p1 k01 @ s3,4) || B(p1 k2 -> s0) ; store io=0
    tp_mc<1,0,2,3,3>(whl, yhi, ylo, acc1, lane, wv);
    tp_yb<1,2,1,0>(x1, Mlds, yhi, ylo, b0, uy, g);
    #pragma unroll
    for (int mt = 0; mt < 2; ++mt)
        *(f32x4*)(opb + wv*32 + mt*16 + qC*4) = acc0[mt][0];
    __syncthreads();

    // R2: C(p1 k2 @ s0) || B(p3 k01 -> s3,4)
    tp_mc<1,2,1,0,3>(whl, yhi, ylo, acc1, lane, wv);
    tp_yb<3,0,2,3>(x1, Mlds, yhi, ylo, b0, uy, g);
    __syncthreads();

    // R3: C(p3 k01) || B(p3 k2 -> s0)
    tp_mc<3,0,2,3,3>(whl, yhi, ylo, acc1, lane, wv);
    tp_yb<3,2,1,0>(x1, Mlds, yhi, ylo, b0, uy, g);
    __syncthreads();

    // R4: C(p3 k2) || B(p6 k01 -> s3,4)
    tp_mc<3,2,1,0,3>(whl, yhi, ylo, acc1, lane, wv);
    tp_yb<6,0,2,3>(x1, Mlds, yhi, ylo, b0, uy, g);
    __syncthreads();

    // R5: C(p6 k01) || B(p6 k2 -> s0)
    tp_mc<6,0,2,3,3>(whl, yhi, ylo, acc1, lane, wv);
    tp_yb<6,2,1,0>(x1, Mlds, yhi, ylo, b0, uy, g);
    __syncthreads();

    // R6: C(p6 k2) || B(p8 k01 -> s3,4)
    tp_mc<6,2,1,0,3>(whl, yhi, ylo, acc1, lane, wv);
    tp_yb<8,0,2,3>(x1, Mlds, yhi, ylo, b0, uy, g);
    __syncthreads();

    // R7: C(p8 k01) || B(p8 k2 -> s0)
    tp_mc<8,0,2,3,3>(whl, yhi, ylo, acc1, lane, wv);
    tp_yb<8,2,1,0>(x1, Mlds, yhi, ylo, b0, uy, g);
    __syncthreads();

    // R8: C(p8 k2 @ s0) || B(p2 k012 -> s2,3,4) ; store io=1
    f32x4 acc2[2][5];
    #pragma unroll
    for (int mt = 0; mt < 2; ++mt)
        #pragma unroll
        for (int k = 0; k < 5; ++k) acc2[mt][k] = f32x4{0.f,0.f,0.f,0.f};
    tp_mc<8,2,1,0,3>(whl, yhi, ylo, acc1, lane, wv);
    tp_yb<2,0,3,2>(x1, Mlds, yhi, ylo, b0, uy, g);
    {
        float b1[24];
        #pragma unroll
        for (int mt = 0; mt < 2; ++mt)
            #pragma unroll
            for (int r = 0; r < 4; ++r)
                #pragma unroll
                for (int k = 0; k < 3; ++k)
                    b1[(mt*4 + r)*3 + k] = acc1[mt][k][r];
        // w = wv*32 + mt*16 + qC*4 + r -> 12 contiguous floats per mt at
        // 128 + w0*3; two 12-float runs per lane
        #pragma unroll
        for (int mt = 0; mt < 2; ++mt) {
            const int w0 = wv*32 + mt*16 + qC*4;
            #pragma unroll
            for (int q = 0; q < 3; ++q)
                *(f32x4*)(opb + 128 + w0*3 + q*4) = *(const f32x4*)(b1 + mt*12 + q*4);
        }
    }
    __syncthreads();

    // R9: C(p2 k012 @ s2-4) || B(p2 k34 -> s0,1)
    tp_mc<2,0,3,2,5>(whl, yhi, ylo, acc2, lane, wv);
    tp_yb<2,3,2,0>(x1, Mlds, yhi, ylo, b0, uy, g);
    __syncthreads();

    // R10: C(p2 k34 @ s0,1) || B(p5 k012 -> s2,3,4)
    tp_mc<2,3,2,0,5>(whl, yhi, ylo, acc2, lane, wv);
    tp_yb<5,0,3,2>(x1, Mlds, yhi, ylo, b0, uy, g);
    __syncthreads();

    // R11: C(p5 k012) || B(p5 k34 -> s0,1)
    tp_mc<5,0,3,2,5>(whl, yhi, ylo, acc2, lane, wv);
    tp_yb<5,3,2,0>(x1, Mlds, yhi, ylo, b0, uy, g);
    __syncthreads();

    // R12: C(p5 k34) || B(p7 k012 -> s2,3,4)
    tp_mc<5,3,2,0,5>(whl, yhi, ylo, acc2, lane, wv);
    tp_yb<7,0,3,2>(x1, Mlds, yhi, ylo, b0, uy, g);
    __syncthreads();

    // R13: C(p7 k012) || B(p7 k34 -> s0,1)
    tp_mc<7,0,3,2,5>(whl, yhi, ylo, acc2, lane, wv);
    tp_yb<7,3,2,0>(x1, Mlds, yhi, ylo, b0, uy, g);
    __syncthreads();

    // R14: C(p7 k34) || B(p10 k012 -> s2,3,4)
    tp_mc<7,3,2,0,5>(whl, yhi, ylo, acc2, lane, wv);
    tp_yb<10,0,3,2>(x1, Mlds, yhi, ylo, b0, uy, g);
    __syncthreads();

    // R15: C(p10 k012) || B(p10 k34 -> s0,1)
    tp_mc<10,0,3,2,5>(whl, yhi, ylo, acc2, lane, wv);
    tp_yb<10,3,2,0>(x1, Mlds, yhi, ylo, b0, uy, g);
    __syncthreads();

    // R16: C(p10 k34 @ s0,1) ; store io=2
    tp_mc<10,3,2,0,5>(whl, yhi, ylo, acc2, lane, wv);
    {
        float b2[40];
        #pragma unroll
        for (int mt = 0; mt < 2; ++mt)
            #pragma unroll
            for (int r = 0; r < 4; ++r)
                #pragma unroll
                for (int k = 0; k < 5; ++k)
                    b2[(mt*4 + r)*5 + k] = acc2[mt][k][r];
        #pragma unroll
        for (int mt = 0; mt < 2; ++mt) {
            const int w0 = wv*32 + mt*16 + qC*4;
            #pragma unroll
            for (int q = 0; q < 5; ++q)
                *(f32x4*)(opb + 512 + w0*5 + q*4) = *(const f32x4*)(b2 + mt*20 + q*4);
        }
    }
}

// ---- launch ---------------------------------------------------------------
extern "C" void kernel_launch(void* const* d_in, const int* in_sizes, int n_in,
                              void* d_out, int out_size, void* d_ws, size_t ws_size,
                              hipStream_t stream) {
    const float* x1  = (const float*)d_in[0];
    const float* x2  = (const float*)d_in[1];
    const float* wsg = (const float*)d_in[2];
    float* out = (float*)d_out;
    const int B = in_sizes[0] / 1152;   // 32768

    TPConst tc;
    fill_const(tc);   // deterministic; identical on every call (graph-capture safe)

    unsigned short* whl = (unsigned short*)d_ws;   // needs 720896 B

    hipLaunchKernelGGL(w_prep, dim3((WPLANE + 255)/256), dim3(256), 0, stream, wsg, whl);

    dim3 grid(B / BT), block(256);
    hipLaunchKernelGGL(tp_kernel, grid, block, 0, stream, x1, x2, whl, out, tc);
}

// Round 8
// 470.307 us; speedup vs baseline: 1.2301x; 1.2301x over previous
//
#include <hip/hip_runtime.h>
#include <cmath>
#include <complex>

#define BT 16   // batch tile per block
#define NP 11   // number of tensor-product paths

// ---- path metadata (compile-time) ----------------------------------------
// paths in reference order: (i1,i2,io) =
// (0,0,0),(0,1,1),(0,2,2),(1,0,1),(1,1,0),(1,1,2),(1,2,1),(2,0,2),(2,1,1),(2,2,0),(2,2,2)
constexpr int P_N1[NP]   = {1,1,1, 3,3,3,3, 5,5,5,5};              // 2*l1+1
constexpr int P_N2[NP]   = {1,3,5, 1,3,3,5, 1,3,5,5};              // 2*l2+1
constexpr int P_NO[NP]   = {1,3,5, 3,1,5,3, 5,3,1,5};              // 2*lo+1
constexpr int P_S1[NP]   = {0,0,0, 128,128,128,128, 512,512,512,512}; // x1 offset
constexpr int P_S2[NP]   = {0,1,4, 0,1,1,4, 0,1,4,4};              // x2 offset
constexpr int P_MOFF[NP] = {0,1,4,9,18,21,36,45,70,85,90};         // M LDS offsets (sizes no*n1, total 115)
constexpr int P_W3J[NP]  = {0,1,10,35,44,53,98,143,168,213,238};   // w3j offsets (sizes n1*n2*no, total 363)

#define WPLANE 180224          // 11*128*128 bf16 elements per plane (hi / lo)

struct TPConst {
    float w3j[363];
    float sqa[11];
};

// ---- host-side exact mirror of the reference w3j computation -------------
namespace {

double hfact(int n) { double r = 1.0; for (int i = 2; i <= n; ++i) r *= (double)i; return r; }

void hsu2cg(int j1, int j2, int j3, double* C) {
    const int d2 = 2*j2+1, d3 = 2*j3+1, d1 = 2*j1+1;
    for (int i = 0; i < d1*d2*d3; ++i) C[i] = 0.0;
    for (int m1 = -j1; m1 <= j1; ++m1)
        for (int m2 = -j2; m2 <= j2; ++m2) {
            const int m3 = m1 + m2;
            if (m3 < -j3 || m3 > j3) continue;
            double pref = std::sqrt((2*j3+1) * hfact(j3+j1-j2) * hfact(j3-j1+j2) * hfact(j1+j2-j3) / hfact(j1+j2+j3+1));
            pref *= std::sqrt(hfact(j3+m3)*hfact(j3-m3)*hfact(j1-m1)*hfact(j1+m1)*hfact(j2-m2)*hfact(j2+m2));
            double s = 0.0;
            for (int k = 0; k <= j1+j2-j3; ++k) {
                if (j1-m1-k < 0 || j2+m2-k < 0 || j3-j2+m1+k < 0 || j3-j1-m2+k < 0) continue;
                double d = hfact(k)*hfact(j1+j2-j3-k)*hfact(j1-m1-k)*hfact(j2+m2-k)*hfact(j3-j2+m1+k)*hfact(j3-j1-m2+k);
                s += ((k & 1) ? -1.0 : 1.0) / d;
            }
            C[((j1+m1)*d2 + (j2+m2))*d3 + (j3+m3)] = pref * s;
        }
}

void hrealbasis(int l, std::complex<double>* q) {  // (2l+1)x(2l+1), row-major
    const int d = 2*l+1;
    for (int i = 0; i < d*d; ++i) q[i] = 0.0;
    const double is2 = 1.0 / std::sqrt(2.0);
    for (int m = -l; m < 0; ++m) {
        q[(l+m)*d + (l - m)] = is2;                                  // l+|m| = l-m for m<0
        q[(l+m)*d + (l + m)] = std::complex<double>(0.0, -is2);      // l-|m| = l+m
    }
    q[l*d + l] = 1.0;
    for (int m = 1; m <= l; ++m) {
        const double sgn = (m & 1) ? -1.0 : 1.0;
        q[(l+m)*d + (l + m)] = sgn * is2;
        q[(l+m)*d + (l - m)] = std::complex<double>(0.0, sgn * is2);
    }
    std::complex<double> ph(1.0, 0.0);
    const std::complex<double> mi(0.0, -1.0);
    for (int i = 0; i < l; ++i) ph *= mi;   // (-i)^l
    for (int i = 0; i < d*d; ++i) q[i] *= ph;
}

void hw3j(int l1, int l2, int l3, float* out) {
    const int d1 = 2*l1+1, d2 = 2*l2+1, d3 = 2*l3+1;
    double C[125];
    hsu2cg(l1, l2, l3, C);
    std::complex<double> Q1[25], Q2[25], Q3[25];
    hrealbasis(l1, Q1); hrealbasis(l2, Q2); hrealbasis(l3, Q3);
    double R[125]; double norm2 = 0.0;
    for (int j = 0; j < d1; ++j)
        for (int l = 0; l < d2; ++l)
            for (int m = 0; m < d3; ++m) {
                std::complex<double> s(0.0, 0.0);
                for (int i = 0; i < d1; ++i)
                    for (int k = 0; k < d2; ++k)
                        for (int n = 0; n < d3; ++n)
                            s += Q1[i*d1 + j] * Q2[k*d2 + l] * std::conj(Q3[n*d3 + m]) * C[(i*d2 + k)*d3 + n];
                R[(j*d2 + l)*d3 + m] = s.real();
                norm2 += s.real() * s.real();
            }
    const double inv = 1.0 / std::sqrt(norm2);
    for (int i = 0; i < d1*d2*d3; ++i) out[i] = (float)(R[i] * inv);
}

void fill_const(TPConst& tc) {
    const int L1[NP] = {0,0,0,1,1,1,1,2,2,2,2};
    const int L2[NP] = {0,1,2,0,1,1,2,0,1,2,2};
    const int LO[NP] = {0,1,2,1,0,2,1,2,1,0,2};
    const double den[3] = {384.0, 512.0, 512.0};   // path_normalization='element'
    for (int p = 0; p < NP; ++p) {
        hw3j(L1[p], L2[p], LO[p], tc.w3j + P_W3J[p]);
        tc.sqa[p] = (float)std::sqrt((2.0*LO[p] + 1.0) / den[LO[p]]);
    }
}

}  // namespace

// ---- device types / helpers ----------------------------------------------
typedef __attribute__((ext_vector_type(8))) short  short8v;   // 8 bf16 (4 VGPRs), MFMA A/B frag
typedef __attribute__((ext_vector_type(4))) float  f32x4;     // MFMA C/D frag

__device__ __forceinline__ unsigned fbits(float f) { return __builtin_bit_cast(unsigned, f); }
__device__ __forceinline__ float    bitsf(unsigned u) { return __builtin_bit_cast(float, u); }

// hi/lo bf16 split: hi = truncated top-16, lo = bf16(exact residual).
// Captured precision ~17 mantissa bits.
__device__ __forceinline__ void splitf(float f, unsigned short& h, unsigned short& l) {
    const unsigned ub = fbits(f);
    h = (unsigned short)(ub >> 16);
    const float r = f - bitsf(ub & 0xFFFF0000u);
    l = (unsigned short)(fbits(r) >> 16);
}

// ---- W prep kernel: wsg [p][u][w] fp32 -> whl [p][w][u] bf16 hi + lo -----
// Runs once per launch (720896 B in d_ws). Removes the per-wave in-register
// W split (was ~40% of round-6 VALU, 2048x redundant).
__global__ __launch_bounds__(256)
void w_prep(const float* __restrict__ wsg, unsigned short* __restrict__ whl)
{
    const int idx = blockIdx.x*256 + threadIdx.x;   // [p][w][u]
    if (idx >= WPLANE) return;
    const int u = idx & 127, w = (idx >> 7) & 127, p = idx >> 14;
    const float f = wsg[(p*128 + u)*128 + w];
    unsigned short h, l;
    splitf(f, h, l);
    whl[idx] = h;
    whl[WPLANE + idx] = l;
}

// ---- phase B: y into LDS slot(s) ------------------------------------------
// ROUND-4 LESSON (rule #20): all path/slot/k indices are template params.
// y layout: [slot][b][u] bf16 (hi+lo planes), u XOR-swizzled by (b&7)<<3
// (un-swizzled, the 16 b-rows at 256 B stride are a 16-way conflict on the
// frag reads; swizzled it's 2-way = free [m136]).
template<int P, int K0, int NOK, int S0>
__device__ __forceinline__ void tp_yb(
    const float* __restrict__ x1, const float (*__restrict__ Mlds)[116],
    unsigned short* __restrict__ yhi, unsigned short* __restrict__ ylo,
    long b0, int uy, int g)
{
    constexpr int n1 = P_N1[P];
    #pragma unroll
    for (int bb = 0; bb < 8; ++bb) {
        const int b = g*8 + bb;
        const float* xp = x1 + (b0 + b)*1152 + P_S1[P] + uy*n1;
        float xv[5];
        #pragma unroll
        for (int i = 0; i < n1; ++i) xv[i] = xp[i];
        const int us = uy ^ ((b & 7) << 3);
        #pragma unroll
        for (int kl = 0; kl < NOK; ++kl) {
            float yv = 0.f;
            #pragma unroll
            for (int i = 0; i < n1; ++i)
                yv += Mlds[b][P_MOFF[P] + (K0 + kl)*n1 + i] * xv[i];
            unsigned short h, l;
            splitf(yv, h, l);
            yhi[((S0 + kl)*16 + b)*128 + us] = h;
            ylo[((S0 + kl)*16 + b)*128 + us] = l;
        }
    }
}

// ---- phase C: MFMA unit ---------------------------------------------------
// GEMM tile per block: C[w,(b,k)] += sum_u W_p[u,w] * y[b,u,k]
// mfma_f32_16x16x32_bf16; A-frag = prepped Whi/Wlo (16B contiguous load,
// L2-resident), B-frag from LDS slots. fp32 via 3 products (hh + hl + lh).
// Lane layouts verified on HW (round 6 passed at fp32-level absmax).
template<int P, int K0, int NOK, int S0, int NA>
__device__ __forceinline__ void tp_mc(
    const unsigned short* __restrict__ whl,
    const unsigned short* __restrict__ yhi, const unsigned short* __restrict__ ylo,
    f32x4 (&acc)[2][NA], int lane, int wv)
{
    const int bC = lane & 15, qC = lane >> 4;
    #pragma unroll
    for (int k4 = 0; k4 < 4; ++k4) {
        const int ubase = k4*32 + qC*8;
        short8v Ah[2], Al[2];
        #pragma unroll
        for (int mt = 0; mt < 2; ++mt) {
            const int aoff = (P*128 + (wv*32 + mt*16 + bC))*128 + ubase;
            Ah[mt] = *(const short8v*)(whl + aoff);
            Al[mt] = *(const short8v*)(whl + WPLANE + aoff);
        }
        const int uoff = ubase ^ ((bC & 7) << 3);
        #pragma unroll
        for (int kl = 0; kl < NOK; ++kl) {
            const int ridx = ((S0 + kl)*16 + bC)*128 + uoff;
            const short8v Bh = *(const short8v*)(yhi + ridx);
            const short8v Bl = *(const short8v*)(ylo + ridx);
            #pragma unroll
            for (int mt = 0; mt < 2; ++mt) {
                acc[mt][K0+kl] = __builtin_amdgcn_mfma_f32_16x16x32_bf16(Ah[mt], Bh, acc[mt][K0+kl], 0, 0, 0);
                acc[mt][K0+kl] = __builtin_amdgcn_mfma_f32_16x16x32_bf16(Ah[mt], Bl, acc[mt][K0+kl], 0, 0, 0);
                acc[mt][K0+kl] = __builtin_amdgcn_mfma_f32_16x16x32_bf16(Al[mt], Bh, acc[mt][K0+kl], 0, 0, 0);
            }
        }
    }
}

// ---- main kernel ----------------------------------------------------------
// STRUCTURE NOTE (measured r6 vs r7): short HOMOGENEOUS barrier regions
// (B-only / C-only alternation, r6: 301 us) beat merged C(i)||B(i+1)
// regions (r7: 425 us) — the merged region serializes A-loads -> MFMA ->
// x1-loads -> fmacs -> full drain per wave at a ~128-reg liveset, and
// pipe-busy sum drops 41% -> 22%. Cross-block phase skew over 3 blocks/CU
// already provides the MFMA||VALU overlap. Do NOT re-merge regions.
// Pass-0's three no=1 paths DO merge safely (disjoint slots, homogeneous):
// 6 regions -> 2.
// (256,2) caps VGPR at 128 (calibrated r1-r3: (256,3)->84 spills huge;
// plain->132 crosses the 128 HW allocation boundary and halves residency).
__global__ __launch_bounds__(256, 2)
void tp_kernel(const float* __restrict__ x1, const float* __restrict__ x2,
               const unsigned short* __restrict__ whl, float* __restrict__ out,
               TPConst tc)
{
    __shared__ float Mlds[BT][116];                         // per-b M matrices (scaled), 115 used
    __shared__ __align__(16) unsigned short yhi[5*16*128];  // y hi-plane, [slot][b][u] swizzled
    __shared__ __align__(16) unsigned short ylo[5*16*128];  // y lo-plane

    const int t = threadIdx.x;
    const long b0 = (long)blockIdx.x * BT;

    // Phase A: M_p[b][k][i] = sum_j C_p[i][j][k] * x2[b][s2+j], scaled
    if (t < BT) {
        float x2v[9];
        #pragma unroll
        for (int j = 0; j < 9; ++j) x2v[j] = x2[(b0 + t)*9 + j];
        #pragma unroll
        for (int p = 0; p < NP; ++p) {
            const int n1 = P_N1[p], n2 = P_N2[p], no = P_NO[p];
            const float sqa = tc.sqa[p];
            #pragma unroll
            for (int k = 0; k < no; ++k)
                #pragma unroll
                for (int i = 0; i < n1; ++i) {
                    float m = 0.f;
                    #pragma unroll
                    for (int j = 0; j < n2; ++j)
                        m += tc.w3j[P_W3J[p] + (i*n2 + j)*no + k] * x2v[P_S2[p] + j];
                    Mlds[t][P_MOFF[p] + k*n1 + i] = m * sqa;
                }
        }
    }

    const int uy = t & 127, g = t >> 7;      // phase B roles
    const int lane = t & 63, wv = t >> 6;    // phase C roles
    const int bC = lane & 15, qC = lane >> 4;
    float* opb = out + (b0 + bC)*1152;

    __syncthreads();

    // ---- pass 0: io=0 (no=1), paths 0,4,9 — merged B region, merged C ----
    {
        tp_yb<0,0,1,0>(x1, Mlds, yhi, ylo, b0, uy, g);
        tp_yb<4,0,1,1>(x1, Mlds, yhi, ylo, b0, uy, g);
        tp_yb<9,0,1,2>(x1, Mlds, yhi, ylo, b0, uy, g);
        __syncthreads();

        f32x4 acc0[2][1];
        #pragma unroll
        for (int mt = 0; mt < 2; ++mt) acc0[mt][0] = f32x4{0.f,0.f,0.f,0.f};
        tp_mc<0,0,1,0,1>(whl, yhi, ylo, acc0, lane, wv);
        tp_mc<4,0,1,1,1>(whl, yhi, ylo, acc0, lane, wv);
        tp_mc<9,0,1,2,1>(whl, yhi, ylo, acc0, lane, wv);
        __syncthreads();

        #pragma unroll
        for (int mt = 0; mt < 2; ++mt)
            *(f32x4*)(opb + wv*32 + mt*16 + qC*4) = acc0[mt][0];
    }

    // ---- pass 1: io=1 (no=3), paths 1,3,6,8 — per-path B;bar;C;bar -------
    {
        f32x4 acc1[2][3];
        #pragma unroll
        for (int mt = 0; mt < 2; ++mt)
            #pragma unroll
            for (int k = 0; k < 3; ++k) acc1[mt][k] = f32x4{0.f,0.f,0.f,0.f};

        tp_yb<1,0,3,0>(x1, Mlds, yhi, ylo, b0, uy, g);
        __syncthreads();
        tp_mc<1,0,3,0,3>(whl, yhi, ylo, acc1, lane, wv);
        __syncthreads();

        tp_yb<3,0,3,0>(x1, Mlds, yhi, ylo, b0, uy, g);
        __syncthreads();
        tp_mc<3,0,3,0,3>(whl, yhi, ylo, acc1, lane, wv);
        __syncthreads();

        tp_yb<6,0,3,0>(x1, Mlds, yhi, ylo, b0, uy, g);
        __syncthreads();
        tp_mc<6,0,3,0,3>(whl, yhi, ylo, acc1, lane, wv);
        __syncthreads();

        tp_yb<8,0,3,0>(x1, Mlds, yhi, ylo, b0, uy, g);
        __syncthreads();
        tp_mc<8,0,3,0,3>(whl, yhi, ylo, acc1, lane, wv);
        __syncthreads();

        float b1[24];
        #pragma unroll
        for (int mt = 0; mt < 2; ++mt)
            #pragma unroll
            for (int r = 0; r < 4; ++r)
                #pragma unroll
                for (int k = 0; k < 3; ++k)
                    b1[(mt*4 + r)*3 + k] = acc1[mt][k][r];
        #pragma unroll
        for (int mt = 0; mt < 2; ++mt) {
            const int w0 = wv*32 + mt*16 + qC*4;
            #pragma unroll
            for (int q = 0; q < 3; ++q)
                *(f32x4*)(opb + 128 + w0*3 + q*4) = *(const f32x4*)(b1 + mt*12 + q*4);
        }
    }

    // ---- pass 2: io=2 (no=5), paths 2,5,7,10 — per-path B;bar;C;bar ------
    {
        f32x4 acc2[2][5];
        #pragma unroll
        for (int mt = 0; mt < 2; ++mt)
            #pragma unroll
            for (int k = 0; k < 5; ++k) acc2[mt][k] = f32x4{0.f,0.f,0.f,0.f};

        tp_yb<2,0,5,0>(x1, Mlds, yhi, ylo, b0, uy, g);
        __syncthreads();
        tp_mc<2,0,5,0,5>(whl, yhi, ylo, acc2, lane, wv);
        __syncthreads();

        tp_yb<5,0,5,0>(x1, Mlds, yhi, ylo, b0, uy, g);
        __syncthreads();
        tp_mc<5,0,5,0,5>(whl, yhi, ylo, acc2, lane, wv);
        __syncthreads();

        tp_yb<7,0,5,0>(x1, Mlds, yhi, ylo, b0, uy, g);
        __syncthreads();
        tp_mc<7,0,5,0,5>(whl, yhi, ylo, acc2, lane, wv);
        __syncthreads();

        tp_yb<10,0,5,0>(x1, Mlds, yhi, ylo, b0, uy, g);
        __syncthreads();
        tp_mc<10,0,5,0,5>(whl, yhi, ylo, acc2, lane, wv);
        __syncthreads();

        float b2[40];
        #pragma unroll
        for (int mt = 0; mt < 2; ++mt)
            #pragma unroll
            for (int r = 0; r < 4; ++r)
                #pragma unroll
                for (int k = 0; k < 5; ++k)
                    b2[(mt*4 + r)*5 + k] = acc2[mt][k][r];
        #pragma unroll
        for (int mt = 0; mt < 2; ++mt) {
            const int w0 = wv*32 + mt*16 + qC*4;
            #pragma unroll
            for (int q = 0; q < 5; ++q)
                *(f32x4*)(opb + 512 + w0*5 + q*4) = *(const f32x4*)(b2 + mt*20 + q*4);
        }
    }
}

// ---- launch ---------------------------------------------------------------
extern "C" void kernel_launch(void* const* d_in, const int* in_sizes, int n_in,
                              void* d_out, int out_size, void* d_ws, size_t ws_size,
                              hipStream_t stream) {
    const float* x1  = (const float*)d_in[0];
    const float* x2  = (const float*)d_in[1];
    const float* wsg = (const float*)d_in[2];
    float* out = (float*)d_out;
    const int B = in_sizes[0] / 1152;   // 32768

    TPConst tc;
    fill_const(tc);   // deterministic; identical on every call (graph-capture safe)

    unsigned short* whl = (unsigned short*)d_ws;   // needs 720896 B

    hipLaunchKernelGGL(w_prep, dim3((WPLANE + 255)/256), dim3(256), 0, stream, wsg, whl);

    dim3 grid(B / BT), block(256);
    hipLaunchKernelGGL(tp_kernel, grid, block, 0, stream, x1, x2, whl, out, tc);
}